// Round 1
// baseline (2221.407 us; speedup 1.0000x reference)
//
#include <hip/hip_runtime.h>

#define HW 512
#define NPIX (HW*HW)
#define NSAMP 64
#define KSEL 2621

// ---------------------------------------------------------------------------
// conv forward (fp64 accumulate) fused with level-1 histogram of abs bits.
// Level 1 bins = bits[30:20] (2048 bins).
// ---------------------------------------------------------------------------
template<int K>
__global__ __launch_bounds__(256) void conv_fwd_hist(
    const float* __restrict__ x, const float* __restrict__ w,
    float* __restrict__ sim, unsigned* __restrict__ hist)
{
  constexpr int PAD = K/2;
  __shared__ double wsm[K*K];
  __shared__ unsigned lh[2048];
  const int tid = threadIdx.y*64 + threadIdx.x;
  if (tid < K*K) wsm[tid] = (double)w[tid];
  for (int i = tid; i < 2048; i += 256) lh[i] = 0;
  __syncthreads();

  const int s  = blockIdx.z;
  const int px = blockIdx.x*64 + threadIdx.x;
  const int py = blockIdx.y*4  + threadIdx.y;
  const float* __restrict__ xs = x + (size_t)s*NPIX;

  double acc = 0.0;
  const bool interior = (blockIdx.x > 0) && (blockIdx.x < gridDim.x-1) &&
                        (py >= PAD) && (py < HW-PAD);
  if (interior) {
    #pragma unroll
    for (int i = 0; i < K; ++i) {
      const int yy = py + i - PAD;
      #pragma unroll
      for (int j = 0; j < K; ++j) {
        const int xx = px + j - PAD;
        acc = fma((double)xs[yy*HW + xx], wsm[i*K+j], acc);
      }
    }
  } else {
    #pragma unroll
    for (int i = 0; i < K; ++i) {
      const int yy = py + i - PAD;
      const bool yok = (yy >= 0) && (yy < HW);
      #pragma unroll
      for (int j = 0; j < K; ++j) {
        const int xx = px + j - PAD;
        const bool ok = yok && (xx >= 0) && (xx < HW);
        const float v = ok ? xs[yy*HW + xx] : 0.0f;
        acc = fma((double)v, wsm[i*K+j], acc);
      }
    }
  }

  const float sv = (float)acc;
  sim[(size_t)s*NPIX + (size_t)py*HW + px] = sv;
  const unsigned bits = __float_as_uint(sv) & 0x7fffffffu;
  atomicAdd(&lh[bits >> 20], 1u);
  __syncthreads();

  unsigned* __restrict__ gh = hist + s*2048;
  for (int i = tid; i < 2048; i += 256) {
    const unsigned c = lh[i];
    if (c) atomicAdd(&gh[i], c);
  }
}

// ---------------------------------------------------------------------------
// Refinement histograms.
// LEVEL 2: among elements with bits[30:20]==prefix, hist of bits[19:9] (2048).
// LEVEL 3: among elements with bits[30:9]==prefix,  hist of bits[8:0]  (512).
// ---------------------------------------------------------------------------
template<int LEVEL>
__global__ __launch_bounds__(256) void hist_refine(
    const float* __restrict__ sim, const unsigned* __restrict__ prefix,
    unsigned* __restrict__ hist)
{
  constexpr int BINS = (LEVEL == 2) ? 2048 : 512;
  __shared__ unsigned lh[BINS];
  const int tid = threadIdx.x;
  for (int i = tid; i < BINS; i += 256) lh[i] = 0;
  __syncthreads();

  const int s = blockIdx.y;
  const unsigned pfx = prefix[s];
  const float4* __restrict__ p =
      (const float4*)(sim + (size_t)s*NPIX) + (size_t)blockIdx.x*1024;

  #pragma unroll
  for (int k = 0; k < 4; ++k) {
    const float4 v = p[k*256 + tid];
    const float f[4] = {v.x, v.y, v.z, v.w};
    #pragma unroll
    for (int e = 0; e < 4; ++e) {
      const unsigned bits = __float_as_uint(f[e]) & 0x7fffffffu;
      if (LEVEL == 2) {
        if ((bits >> 20) == (pfx >> 20)) atomicAdd(&lh[(bits >> 9) & 0x7ffu], 1u);
      } else {
        if ((bits >> 9) == (pfx >> 9)) atomicAdd(&lh[bits & 0x1ffu], 1u);
      }
    }
  }
  __syncthreads();

  unsigned* __restrict__ gh = hist + s*2048;
  for (int i = tid; i < BINS; i += 256) {
    const unsigned c = lh[i];
    if (c) atomicAdd(&gh[i], c);
  }
}

// ---------------------------------------------------------------------------
// Scan a level's histogram (descending bins = descending values), pick the bin
// containing the k-th largest, update prefix/krem; level 3 emits final
// threshold bit pattern. Also zeroes the histogram for the next pass.
// ---------------------------------------------------------------------------
template<int LEVEL>
__global__ __launch_bounds__(256) void scan_level(
    unsigned* __restrict__ hist, unsigned* __restrict__ prefix,
    unsigned* __restrict__ krem, unsigned* __restrict__ thbits)
{
  constexpr int BINS  = (LEVEL == 3) ? 512 : 2048;
  constexpr int C     = BINS / 256;
  constexpr int SHIFT = (LEVEL == 1) ? 20 : (LEVEL == 2) ? 9 : 0;
  const int s = blockIdx.x;
  const int t = threadIdx.x;
  unsigned* __restrict__ h = hist + s*2048;

  __shared__ unsigned part[256];
  unsigned sum = 0;
  #pragma unroll
  for (int i = 0; i < C; ++i) sum += h[t*C + i];
  part[t] = sum;
  __syncthreads();

  if (t == 0) {
    const unsigned kr = (LEVEL == 1) ? (unsigned)KSEL : krem[s];
    unsigned cum = 0;
    int sc = 0;
    for (int c = 255; c >= 0; --c) {
      if (cum + part[c] >= kr) { sc = c; break; }
      cum += part[c];
    }
    unsigned cum2 = cum;
    int sb = sc*C;
    for (int b = sc*C + C - 1; b >= sc*C; --b) {
      if (cum2 + h[b] >= kr) { sb = b; break; }
      cum2 += h[b];
    }
    if (LEVEL == 1)      { prefix[s] = ((unsigned)sb) << SHIFT; krem[s] = kr - cum2; }
    else if (LEVEL == 2) { prefix[s] |= ((unsigned)sb) << SHIFT; krem[s] = kr - cum2; }
    else                 { thbits[s] = prefix[s] | (unsigned)sb; }
  }
  __syncthreads();
  for (int i = t; i < 2048; i += 256) h[i] = 0;
}

// ---------------------------------------------------------------------------
// conv of thresholded activations, accumulated into out (fp64 accumulate).
// act(q) = (|sim(q)| bits >= thbits) ? sim(q) : 0
// ---------------------------------------------------------------------------
template<int K, bool FIRST>
__global__ __launch_bounds__(256) void conv_bwd(
    const float* __restrict__ sim, const float* __restrict__ w,
    const unsigned* __restrict__ thbits, float* __restrict__ out)
{
  constexpr int PAD = K/2;
  __shared__ double wsm[K*K];
  const int tid = threadIdx.y*64 + threadIdx.x;
  if (tid < K*K) wsm[tid] = (double)w[tid];
  __syncthreads();

  const int s  = blockIdx.z;
  const unsigned th = thbits[s];
  const int px = blockIdx.x*64 + threadIdx.x;
  const int py = blockIdx.y*4  + threadIdx.y;
  const float* __restrict__ ss = sim + (size_t)s*NPIX;

  double acc = 0.0;
  const bool interior = (blockIdx.x > 0) && (blockIdx.x < gridDim.x-1) &&
                        (py >= PAD) && (py < HW-PAD);
  if (interior) {
    #pragma unroll
    for (int i = 0; i < K; ++i) {
      const int yy = py + i - PAD;
      #pragma unroll
      for (int j = 0; j < K; ++j) {
        const int xx = px + j - PAD;
        float v = ss[yy*HW + xx];
        const unsigned b = __float_as_uint(v) & 0x7fffffffu;
        if (b < th) v = 0.0f;
        acc = fma((double)v, wsm[i*K+j], acc);
      }
    }
  } else {
    #pragma unroll
    for (int i = 0; i < K; ++i) {
      const int yy = py + i - PAD;
      const bool yok = (yy >= 0) && (yy < HW);
      #pragma unroll
      for (int j = 0; j < K; ++j) {
        const int xx = px + j - PAD;
        const bool ok = yok && (xx >= 0) && (xx < HW);
        float v = ok ? ss[yy*HW + xx] : 0.0f;
        const unsigned b = __float_as_uint(v) & 0x7fffffffu;
        if (b < th) v = 0.0f;
        acc = fma((double)v, wsm[i*K+j], acc);
      }
    }
  }

  const size_t o = (size_t)s*NPIX + (size_t)py*HW + px;
  const float r = (float)acc;
  out[o] = FIRST ? r : out[o] + r;
}

// ---------------------------------------------------------------------------
extern "C" void kernel_launch(void* const* d_in, const int* in_sizes, int n_in,
                              void* d_out, int out_size, void* d_ws, size_t ws_size,
                              hipStream_t stream)
{
  const float* x  = (const float*)d_in[0];
  const float* w3 = (const float*)d_in[1];
  const float* w5 = (const float*)d_in[2];
  const float* w7 = (const float*)d_in[3];
  float* out = (float*)d_out;

  char* ws = (char*)d_ws;
  float* sim = (float*)ws;                                        // 64 MB
  unsigned* hist   = (unsigned*)(ws + (size_t)NSAMP*NPIX*sizeof(float)); // 512 KB
  unsigned* prefix = hist + NSAMP*2048;
  unsigned* krem   = prefix + NSAMP;
  unsigned* thb    = krem + NSAMP;

  hipMemsetAsync(hist, 0, NSAMP*2048*sizeof(unsigned), stream);

  dim3 cb(64, 4, 1), cg(HW/64, HW/4, NSAMP);
  dim3 rb(256, 1, 1), rg(NPIX/4096, NSAMP, 1);

  // ---- filter 3x3 ----
  conv_fwd_hist<3><<<cg, cb, 0, stream>>>(x, w3, sim, hist);
  scan_level<1><<<NSAMP, 256, 0, stream>>>(hist, prefix, krem, thb);
  hist_refine<2><<<rg, rb, 0, stream>>>(sim, prefix, hist);
  scan_level<2><<<NSAMP, 256, 0, stream>>>(hist, prefix, krem, thb);
  hist_refine<3><<<rg, rb, 0, stream>>>(sim, prefix, hist);
  scan_level<3><<<NSAMP, 256, 0, stream>>>(hist, prefix, krem, thb);
  conv_bwd<3, true><<<cg, cb, 0, stream>>>(sim, w3, thb, out);

  // ---- filter 5x5 ----
  conv_fwd_hist<5><<<cg, cb, 0, stream>>>(x, w5, sim, hist);
  scan_level<1><<<NSAMP, 256, 0, stream>>>(hist, prefix, krem, thb);
  hist_refine<2><<<rg, rb, 0, stream>>>(sim, prefix, hist);
  scan_level<2><<<NSAMP, 256, 0, stream>>>(hist, prefix, krem, thb);
  hist_refine<3><<<rg, rb, 0, stream>>>(sim, prefix, hist);
  scan_level<3><<<NSAMP, 256, 0, stream>>>(hist, prefix, krem, thb);
  conv_bwd<5, false><<<cg, cb, 0, stream>>>(sim, w5, thb, out);

  // ---- filter 7x7 ----
  conv_fwd_hist<7><<<cg, cb, 0, stream>>>(x, w7, sim, hist);
  scan_level<1><<<NSAMP, 256, 0, stream>>>(hist, prefix, krem, thb);
  hist_refine<2><<<rg, rb, 0, stream>>>(sim, prefix, hist);
  scan_level<2><<<NSAMP, 256, 0, stream>>>(hist, prefix, krem, thb);
  hist_refine<3><<<rg, rb, 0, stream>>>(sim, prefix, hist);
  scan_level<3><<<NSAMP, 256, 0, stream>>>(hist, prefix, krem, thb);
  conv_bwd<7, false><<<cg, cb, 0, stream>>>(sim, w7, thb, out);
}

// Round 2
// 506.495 us; speedup vs baseline: 4.3858x; 4.3858x over previous
//
#include <hip/hip_runtime.h>

#define HW 512
#define NPIX (HW*HW)
#define NSAMP 64
#define KSEL 2621
#define TILE 64

// ---------------------------------------------------------------------------
// Forward conv (fp64 accumulate, exact vs fp64 reference) fused with level-1
// histogram of |sim| bit patterns. 64x64 output tile per block, 16 outputs
// per thread (independent accumulator chains), x staged in LDS with halo.
// Level 1 bins = bits[30:20] (2048 bins).
// ---------------------------------------------------------------------------
template<int K>
__global__ __launch_bounds__(256) void conv_fwd_hist(
    const float* __restrict__ x, const float* __restrict__ w,
    float* __restrict__ sim, unsigned* __restrict__ hist)
{
  constexpr int P   = K/2;
  constexpr int TW  = TILE + 2*P;   // tile + halo
  constexpr int TWP = TW + 2;       // padded LDS stride
  __shared__ float xt[TW][TWP];
  __shared__ double wsm[K*K];
  __shared__ unsigned lh[2048];

  const int tid = threadIdx.x;
  if (tid < K*K) wsm[tid] = (double)w[tid];
  for (int i = tid; i < 2048; i += 256) lh[i] = 0;

  const int s  = blockIdx.z;
  const int bx = blockIdx.x * TILE;
  const int by = blockIdx.y * TILE;
  const float* __restrict__ xs = x + (size_t)s*NPIX;

  for (int idx = tid; idx < TW*TW; idx += 256) {
    const int r = idx / TW, c = idx % TW;
    const int gy = by + r - P, gx = bx + c - P;
    float v = 0.0f;
    if (gy >= 0 && gy < HW && gx >= 0 && gx < HW) v = xs[gy*HW + gx];
    xt[r][c] = v;
  }
  __syncthreads();

  const int tx  = tid & 63;         // output col within tile
  const int ty0 = (tid >> 6) * 16;  // first output row within tile

  double acc[16];
  #pragma unroll
  for (int r = 0; r < 16; ++r) acc[r] = 0.0;

  #pragma unroll
  for (int j = 0; j < K; ++j) {
    float col[16 + K - 1];
    #pragma unroll
    for (int y = 0; y < 16 + K - 1; ++y) col[y] = xt[ty0 + y][tx + j];
    #pragma unroll
    for (int i = 0; i < K; ++i) {
      const double wv = wsm[i*K + j];
      #pragma unroll
      for (int r = 0; r < 16; ++r)
        acc[r] = fma((double)col[r + i], wv, acc[r]);
    }
  }

  float* __restrict__ so = sim + (size_t)s*NPIX + (size_t)by*HW + bx;
  #pragma unroll
  for (int r = 0; r < 16; ++r) {
    const float sv = (float)acc[r];
    so[(size_t)(ty0 + r)*HW + tx] = sv;
    const unsigned bits = __float_as_uint(sv) & 0x7fffffffu;
    atomicAdd(&lh[bits >> 20], 1u);
  }
  __syncthreads();

  unsigned* __restrict__ gh = hist + s*2048;
  for (int i = tid; i < 2048; i += 256) {
    const unsigned c = lh[i];
    if (c) atomicAdd(&gh[i], c);
  }
}

// ---------------------------------------------------------------------------
// Refinement histograms (unchanged).
// LEVEL 2: among elements with bits[30:20]==prefix, hist of bits[19:9] (2048).
// LEVEL 3: among elements with bits[30:9]==prefix,  hist of bits[8:0]  (512).
// ---------------------------------------------------------------------------
template<int LEVEL>
__global__ __launch_bounds__(256) void hist_refine(
    const float* __restrict__ sim, const unsigned* __restrict__ prefix,
    unsigned* __restrict__ hist)
{
  constexpr int BINS = (LEVEL == 2) ? 2048 : 512;
  __shared__ unsigned lh[BINS];
  const int tid = threadIdx.x;
  for (int i = tid; i < BINS; i += 256) lh[i] = 0;
  __syncthreads();

  const int s = blockIdx.y;
  const unsigned pfx = prefix[s];
  const float4* __restrict__ p =
      (const float4*)(sim + (size_t)s*NPIX) + (size_t)blockIdx.x*1024;

  #pragma unroll
  for (int k = 0; k < 4; ++k) {
    const float4 v = p[k*256 + tid];
    const float f[4] = {v.x, v.y, v.z, v.w};
    #pragma unroll
    for (int e = 0; e < 4; ++e) {
      const unsigned bits = __float_as_uint(f[e]) & 0x7fffffffu;
      if (LEVEL == 2) {
        if ((bits >> 20) == (pfx >> 20)) atomicAdd(&lh[(bits >> 9) & 0x7ffu], 1u);
      } else {
        if ((bits >> 9) == (pfx >> 9)) atomicAdd(&lh[bits & 0x1ffu], 1u);
      }
    }
  }
  __syncthreads();

  unsigned* __restrict__ gh = hist + s*2048;
  for (int i = tid; i < BINS; i += 256) {
    const unsigned c = lh[i];
    if (c) atomicAdd(&gh[i], c);
  }
}

// ---------------------------------------------------------------------------
// Scan a level's histogram, pick the bin containing the k-th largest, update
// prefix/krem; level 3 emits the final threshold bit pattern. Zeroes hist.
// ---------------------------------------------------------------------------
template<int LEVEL>
__global__ __launch_bounds__(256) void scan_level(
    unsigned* __restrict__ hist, unsigned* __restrict__ prefix,
    unsigned* __restrict__ krem, unsigned* __restrict__ thbits)
{
  constexpr int BINS  = (LEVEL == 3) ? 512 : 2048;
  constexpr int C     = BINS / 256;
  constexpr int SHIFT = (LEVEL == 1) ? 20 : (LEVEL == 2) ? 9 : 0;
  const int s = blockIdx.x;
  const int t = threadIdx.x;
  unsigned* __restrict__ h = hist + s*2048;

  __shared__ unsigned part[256];
  unsigned sum = 0;
  #pragma unroll
  for (int i = 0; i < C; ++i) sum += h[t*C + i];
  part[t] = sum;
  __syncthreads();

  if (t == 0) {
    const unsigned kr = (LEVEL == 1) ? (unsigned)KSEL : krem[s];
    unsigned cum = 0;
    int sc = 0;
    for (int c = 255; c >= 0; --c) {
      if (cum + part[c] >= kr) { sc = c; break; }
      cum += part[c];
    }
    unsigned cum2 = cum;
    int sb = sc*C;
    for (int b = sc*C + C - 1; b >= sc*C; --b) {
      if (cum2 + h[b] >= kr) { sb = b; break; }
      cum2 += h[b];
    }
    if (LEVEL == 1)      { prefix[s] = ((unsigned)sb) << SHIFT; krem[s] = kr - cum2; }
    else if (LEVEL == 2) { prefix[s] |= ((unsigned)sb) << SHIFT; krem[s] = kr - cum2; }
    else                 { thbits[s] = prefix[s] | (unsigned)sb; }
  }
  __syncthreads();
  for (int i = t; i < 2048; i += 256) h[i] = 0;
}

// ---------------------------------------------------------------------------
// Second conv over thresholded activations, fp32 accumulate (selection is
// already fixed; fp32 error ~1e-6 << 0.0039 comparison floor). Threshold is
// applied while staging into LDS, so the inner loop is a clean fp32 conv.
// ---------------------------------------------------------------------------
template<int K, bool FIRST>
__global__ __launch_bounds__(256) void conv_bwd(
    const float* __restrict__ sim, const float* __restrict__ w,
    const unsigned* __restrict__ thbits, float* __restrict__ out)
{
  constexpr int P   = K/2;
  constexpr int TW  = TILE + 2*P;
  constexpr int TWP = TW + 2;
  __shared__ float xt[TW][TWP];
  __shared__ float wsm[K*K];

  const int tid = threadIdx.x;
  if (tid < K*K) wsm[tid] = w[tid];

  const int s  = blockIdx.z;
  const unsigned th = thbits[s];
  const int bx = blockIdx.x * TILE;
  const int by = blockIdx.y * TILE;
  const float* __restrict__ ss = sim + (size_t)s*NPIX;

  for (int idx = tid; idx < TW*TW; idx += 256) {
    const int r = idx / TW, c = idx % TW;
    const int gy = by + r - P, gx = bx + c - P;
    float v = 0.0f;
    if (gy >= 0 && gy < HW && gx >= 0 && gx < HW) {
      v = ss[gy*HW + gx];
      const unsigned b = __float_as_uint(v) & 0x7fffffffu;
      if (b < th) v = 0.0f;
    }
    xt[r][c] = v;
  }
  __syncthreads();

  const int tx  = tid & 63;
  const int ty0 = (tid >> 6) * 16;

  float acc[16];
  #pragma unroll
  for (int r = 0; r < 16; ++r) acc[r] = 0.0f;

  #pragma unroll
  for (int j = 0; j < K; ++j) {
    float col[16 + K - 1];
    #pragma unroll
    for (int y = 0; y < 16 + K - 1; ++y) col[y] = xt[ty0 + y][tx + j];
    #pragma unroll
    for (int i = 0; i < K; ++i) {
      const float wv = wsm[i*K + j];
      #pragma unroll
      for (int r = 0; r < 16; ++r)
        acc[r] = fmaf(col[r + i], wv, acc[r]);
    }
  }

  float* __restrict__ oo = out + (size_t)s*NPIX + (size_t)by*HW + bx;
  #pragma unroll
  for (int r = 0; r < 16; ++r) {
    const size_t o = (size_t)(ty0 + r)*HW + tx;
    oo[o] = FIRST ? acc[r] : oo[o] + acc[r];
  }
}

// ---------------------------------------------------------------------------
extern "C" void kernel_launch(void* const* d_in, const int* in_sizes, int n_in,
                              void* d_out, int out_size, void* d_ws, size_t ws_size,
                              hipStream_t stream)
{
  const float* x  = (const float*)d_in[0];
  const float* w3 = (const float*)d_in[1];
  const float* w5 = (const float*)d_in[2];
  const float* w7 = (const float*)d_in[3];
  float* out = (float*)d_out;

  char* ws = (char*)d_ws;
  float* sim = (float*)ws;                                             // 64 MB
  unsigned* hist   = (unsigned*)(ws + (size_t)NSAMP*NPIX*sizeof(float)); // 512 KB
  unsigned* prefix = hist + NSAMP*2048;
  unsigned* krem   = prefix + NSAMP;
  unsigned* thb    = krem + NSAMP;

  hipMemsetAsync(hist, 0, NSAMP*2048*sizeof(unsigned), stream);

  dim3 cb(256, 1, 1), cg(HW/TILE, HW/TILE, NSAMP);
  dim3 rb(256, 1, 1), rg(NPIX/4096, NSAMP, 1);

  // ---- filter 3x3 ----
  conv_fwd_hist<3><<<cg, cb, 0, stream>>>(x, w3, sim, hist);
  scan_level<1><<<NSAMP, 256, 0, stream>>>(hist, prefix, krem, thb);
  hist_refine<2><<<rg, rb, 0, stream>>>(sim, prefix, hist);
  scan_level<2><<<NSAMP, 256, 0, stream>>>(hist, prefix, krem, thb);
  hist_refine<3><<<rg, rb, 0, stream>>>(sim, prefix, hist);
  scan_level<3><<<NSAMP, 256, 0, stream>>>(hist, prefix, krem, thb);
  conv_bwd<3, true><<<cg, cb, 0, stream>>>(sim, w3, thb, out);

  // ---- filter 5x5 ----
  conv_fwd_hist<5><<<cg, cb, 0, stream>>>(x, w5, sim, hist);
  scan_level<1><<<NSAMP, 256, 0, stream>>>(hist, prefix, krem, thb);
  hist_refine<2><<<rg, rb, 0, stream>>>(sim, prefix, hist);
  scan_level<2><<<NSAMP, 256, 0, stream>>>(hist, prefix, krem, thb);
  hist_refine<3><<<rg, rb, 0, stream>>>(sim, prefix, hist);
  scan_level<3><<<NSAMP, 256, 0, stream>>>(hist, prefix, krem, thb);
  conv_bwd<5, false><<<cg, cb, 0, stream>>>(sim, w5, thb, out);

  // ---- filter 7x7 ----
  conv_fwd_hist<7><<<cg, cb, 0, stream>>>(x, w7, sim, hist);
  scan_level<1><<<NSAMP, 256, 0, stream>>>(hist, prefix, krem, thb);
  hist_refine<2><<<rg, rb, 0, stream>>>(sim, prefix, hist);
  scan_level<2><<<NSAMP, 256, 0, stream>>>(hist, prefix, krem, thb);
  hist_refine<3><<<rg, rb, 0, stream>>>(sim, prefix, hist);
  scan_level<3><<<NSAMP, 256, 0, stream>>>(hist, prefix, krem, thb);
  conv_bwd<7, false><<<cg, cb, 0, stream>>>(sim, w7, thb, out);
}